// Round 7
// baseline (4426.594 us; speedup 1.0000x reference)
//
#include <hip/hip_runtime.h>
#include <hip/hip_bf16.h>
#include <stdint.h>

typedef float  f32x4  __attribute__((ext_vector_type(4)));
typedef __bf16 bf16x8 __attribute__((ext_vector_type(8)));
typedef unsigned short u16x8 __attribute__((ext_vector_type(8)));

__device__ __forceinline__ unsigned short f2bf_rne(float f) {
    uint32_t x = __float_as_uint(f);
    uint32_t r = x + 0x7FFFu + ((x >> 16) & 1u);
    return (unsigned short)(r >> 16);
}

__global__ __launch_bounds__(256) void cvt_f32_bf16(const float* __restrict__ src,
                                                    unsigned short* __restrict__ dst,
                                                    long n) {
    long i0 = ((long)blockIdx.x * blockDim.x + threadIdx.x) * 8;
    long stride = (long)gridDim.x * blockDim.x * 8;
    for (long j = i0; j + 8 <= n; j += stride) {
        float4 v0 = *(const float4*)(src + j);
        float4 v1 = *(const float4*)(src + j + 4);
        u16x8 o;
        o[0] = f2bf_rne(v0.x); o[1] = f2bf_rne(v0.y);
        o[2] = f2bf_rne(v0.z); o[3] = f2bf_rne(v0.w);
        o[4] = f2bf_rne(v1.x); o[5] = f2bf_rne(v1.y);
        o[6] = f2bf_rne(v1.z); o[7] = f2bf_rne(v1.w);
        *(u16x8*)(dst + j) = o;
    }
}

#define GLL(SRC, DST) __builtin_amdgcn_global_load_lds(                      \
    (const __attribute__((address_space(1))) void*)(SRC),                    \
    (__attribute__((address_space(3))) void*)(DST), 16, 0, 0)
#define BARRIER() asm volatile("s_barrier" ::: "memory")
#define WAITV(N) asm volatile("s_waitcnt vmcnt(" #N ")" ::: "memory")
#define WAITL(N) do { asm volatile("s_waitcnt lgkmcnt(" #N ")" ::: "memory"); \
                      __builtin_amdgcn_sched_barrier(0); } while (0)

// Round-2 kernel (proven: 0 bank conflicts, 49% MfmaUtil, 1030us) with ONE
// change: two-level XCD swizzle. Each XCD's 32 concurrent workgroups form an
// 8m x 4n super-tile -> per-K-step L2 working set 384 KB (fits 4 MiB XCD L2),
// A-panels reused 4x and B-panels 8x in L2 instead of streaming from L3/HBM.
__global__ __launch_bounds__(512, 2) void gemm256_8p(
    const unsigned short* __restrict__ A, const unsigned short* __restrict__ B,
    const float* __restrict__ bias, float* __restrict__ C,
    int M, int N, int K) {
    __shared__ __align__(16) char lds[131072];
    const int tid  = threadIdx.x;
    const int lane = tid & 63;
    const int wave = tid >> 6;
    const int wr  = wave >> 2;   // 0..1
    const int wc  = wave & 3;    // 0..3
    const int l15 = lane & 15;
    const int l4  = lane >> 4;

    // ---- workgroup -> tile mapping ----
    const int nwg = gridDim.x;
    const int Nt  = N >> 8;              // n-tiles
    const int Mt  = M >> 8;              // m-tiles
    const int bid = blockIdx.x;
    int tm, tn;
    if ((Mt & 7) == 0 && (Nt & 3) == 0 && (nwg & 255) == 0) {
        // two-level: super-tile = 8m x 4n (32 wgs); XCD x runs q2 = nst/8
        // super-tiles sequentially, 32 wgs of one super-tile concurrently.
        const int nst = nwg >> 5;        // number of super-tiles
        const int q2  = nst >> 3;        // super-tiles per XCD
        const int xc  = bid & 7;
        const int oo  = bid >> 3;        // [0, nwg/8)
        const int idx = oo & 31;         // position within super-tile
        const int h   = oo >> 5;         // which super-tile for this XCD
        const int st  = xc * q2 + h;
        const int Mst = Mt >> 3;         // super-tiles along m
        const int stm = st % Mst;
        const int stn = st / Mst;
        tm = stm * 8 + (idx & 7);
        tn = stn * 4 + (idx >> 3);
    } else {
        // fallback: bijective 1-D chunking (round-2)
        int qq = nwg >> 3, rr = nwg & 7, xc = bid & 7, oo = bid >> 3;
        int wg = (xc < rr ? xc * (qq + 1) : rr * (qq + 1) + (xc - rr) * qq) + oo;
        tm = wg / Nt; tn = wg % Nt;
    }
    const long m0 = (long)tm << 8;
    const long n0 = (long)tn << 8;

    const int colSw = ((tid & 7) ^ ((tid >> 3) & 7)) << 3;
    const int aRow  = tid >> 3;
    const int bWcLo = tid >> 8;
    const int bR    = (tid >> 3) & 31;
    const long Kl = K;

    auto STAGE_A = [&](int buf, int u, int t) {
        char* dst = lds + (buf << 16) + (u << 14) + tid * 16;
        long col = (long)t * 64 + colSw;
#pragma unroll
        for (int i = 0; i < 2; ++i) {
            const unsigned short* src = A + (m0 + i * 128 + u * 64 + aRow) * Kl + col;
            GLL(src, dst + i * 8192);
        }
    };
    auto STAGE_B = [&](int buf, int u, int t) {
        char* dst = lds + (buf << 16) + 32768 + (u << 14) + tid * 16;
        long col = (long)t * 64 + colSw;
#pragma unroll
        for (int i = 0; i < 2; ++i) {
            const unsigned short* src = B + (n0 + (i * 2 + bWcLo) * 64 + u * 32 + bR) * Kl + col;
            GLL(src, dst + i * 8192);
        }
    };
    auto LDA = [&](int buf, int mh, int m, int kk) -> bf16x8 {
        int off = (((m * 16 + l15) * 64 + kk * 32 + l4 * 8) * 2) ^ ((l15 & 7) << 4);
        return *(const bf16x8*)(lds + (buf << 16) + (mh << 14) + (wr << 13) + off);
    };
    auto LDB = [&](int buf, int nh, int n, int kk) -> bf16x8 {
        int off = (((n * 16 + l15) * 64 + kk * 32 + l4 * 8) * 2) ^ ((l15 & 7) << 4);
        return *(const bf16x8*)(lds + (buf << 16) + 32768 + (nh << 14) + (wc << 12) + off);
    };

    f32x4 acc[8][4] = {};
    bf16x8 afA[4][2], afB[4][2], afA2[4][2], afB2[4][2];
    bf16x8 bqA[2][2], bqB[2][2], bqA2[2][2], bqB2[2][2];

    auto RD_A = [&](bf16x8 (&d)[4][2], int buf, int mh) {
#pragma unroll
        for (int m = 0; m < 4; ++m) { d[m][0] = LDA(buf, mh, m, 0); d[m][1] = LDA(buf, mh, m, 1); }
    };
    auto RD_B = [&](bf16x8 (&d)[2][2], int buf, int nh) {
#pragma unroll
        for (int n = 0; n < 2; ++n) { d[n][0] = LDB(buf, nh, n, 0); d[n][1] = LDB(buf, nh, n, 1); }
    };
    auto MFMA_Q = [&](bf16x8 (&af)[4][2], bf16x8 (&bq)[2][2], int mo, int no) {
        __builtin_amdgcn_s_setprio(1);
#pragma unroll
        for (int kk = 0; kk < 2; ++kk)
#pragma unroll
            for (int m = 0; m < 4; ++m)
#pragma unroll
                for (int n = 0; n < 2; ++n)
                    acc[mo + m][no + n] = __builtin_amdgcn_mfma_f32_16x16x32_bf16(
                        af[m][kk], bq[n][kk], acc[mo + m][no + n], 0, 0, 0);
        __builtin_amdgcn_s_setprio(0);
    };

    const int NT = K >> 6;

    // prologue: stage tiles 0 (buf0) and 1 (buf1); leave last 4 loads in flight
    STAGE_A(0, 0, 0); STAGE_B(0, 0, 0); STAGE_B(0, 1, 0); STAGE_A(0, 1, 0);
    STAGE_A(1, 0, 1); STAGE_B(1, 0, 1); STAGE_B(1, 1, 1); STAGE_A(1, 1, 1);
    WAITV(4);
    BARRIER();
    RD_A(afA, 0, 0);   // A0 @ tile0
    RD_B(bqA, 0, 0);   // B0 @ tile0

    for (int t = 0; t + 3 < NT; t += 2) {
        // P1: Q00(e) = afA x bqA ; prefetch bqB(B1@e) ; stage A0e,B0e(t+2)
        RD_B(bqB, 0, 1);
        STAGE_A(0, 0, t + 2); STAGE_B(0, 0, t + 2);
        BARRIER(); WAITL(4);
        MFMA_Q(afA, bqA, 0, 0);
        BARRIER();
        // P2: Q01(e) = afA x bqB ; prefetch afB(A1@e) ; stage B1e(t+2)
        RD_A(afB, 0, 1);
        STAGE_B(0, 1, t + 2);
        BARRIER(); WAITL(8);
        MFMA_Q(afA, bqB, 0, 2);
        BARRIER();
        // P3: Q11(e) = afB x bqB ; prefetch afA2(A0@o) ; stage A1e(t+2)
        RD_A(afA2, 1, 0);
        STAGE_A(0, 1, t + 2);
        BARRIER(); WAITL(8);
        MFMA_Q(afB, bqB, 4, 2);
        BARRIER();
        // P4: Q10(e) = afB x bqA ; prefetch bqA2(B0@o) ; stage A0o(t+3) ; vmcnt(6)
        RD_B(bqA2, 1, 0);
        STAGE_A(1, 0, t + 3);
        WAITV(6);
        BARRIER(); WAITL(12);
        MFMA_Q(afB, bqA, 4, 0);
        BARRIER();
        // P5: Q00(o) = afA2 x bqA2 ; prefetch bqB2(B1@o) ; stage B0o(t+3)
        RD_B(bqB2, 1, 1);
        STAGE_B(1, 0, t + 3);
        BARRIER(); WAITL(4);
        MFMA_Q(afA2, bqA2, 0, 0);
        BARRIER();
        // P6: Q01(o) = afA2 x bqB2 ; prefetch afB2(A1@o) ; stage B1o(t+3)
        RD_A(afB2, 1, 1);
        STAGE_B(1, 1, t + 3);
        BARRIER(); WAITL(8);
        MFMA_Q(afA2, bqB2, 0, 2);
        BARRIER();
        // P7: Q11(o) = afB2 x bqB2 ; prefetch afA(A0@e, t+2) ; stage A1o(t+3)
        RD_A(afA, 0, 0);
        STAGE_A(1, 1, t + 3);
        BARRIER(); WAITL(8);
        MFMA_Q(afB2, bqB2, 4, 2);
        BARRIER();
        // P8: Q10(o) = afB2 x bqA2 ; prefetch bqA(B0@e, t+2) ; vmcnt(4)
        RD_B(bqA, 0, 0);
        WAITV(4);
        BARRIER(); WAITL(12);
        MFMA_Q(afB2, bqA2, 4, 0);
        BARRIER();
    }

    // tail: tiles NT-2 (buf0), NT-1 (buf1) — no stages, no cross-iter prefetch
    {
        RD_B(bqB, 0, 1);
        BARRIER(); WAITL(4);
        MFMA_Q(afA, bqA, 0, 0);
        BARRIER();
        RD_A(afB, 0, 1);
        BARRIER(); WAITL(8);
        MFMA_Q(afA, bqB, 0, 2);
        BARRIER();
        RD_A(afA2, 1, 0);
        BARRIER(); WAITL(8);
        MFMA_Q(afB, bqB, 4, 2);
        BARRIER();
        RD_B(bqA2, 1, 0);
        WAITV(0);
        BARRIER(); WAITL(12);
        MFMA_Q(afB, bqA, 4, 0);
        BARRIER();
        RD_B(bqB2, 1, 1);
        BARRIER(); WAITL(4);
        MFMA_Q(afA2, bqA2, 0, 0);
        BARRIER();
        RD_A(afB2, 1, 1);
        BARRIER(); WAITL(8);
        MFMA_Q(afA2, bqB2, 0, 2);
        BARRIER();
        BARRIER(); WAITL(0);
        MFMA_Q(afB2, bqB2, 4, 2);
        BARRIER();
        BARRIER(); WAITL(0);
        MFMA_Q(afB2, bqA2, 4, 0);
        BARRIER();
    }

    // epilogue: D mapping col = l15, row = l4*4 + j within each 16x16 fragment
#pragma unroll
    for (int nf = 0; nf < 4; ++nf) {
        const long col = n0 + wc * 64 + nf * 16 + l15;
        const float bv = bias[col];
#pragma unroll
        for (int mf = 0; mf < 8; ++mf) {
            float* Cp = C + (m0 + wr * 128 + mf * 16 + l4 * 4) * (long)N + col;
#pragma unroll
            for (int j = 0; j < 4; ++j)
                Cp[(long)j * N] = acc[mf][nf][j] + bv;
        }
    }
}

// fallback: m97-structure 128x128 (verified round 1)
__global__ __launch_bounds__(256) void gemm_bt_bias(const unsigned short* __restrict__ A,
                                                    const unsigned short* __restrict__ B,
                                                    const float* __restrict__ bias,
                                                    float* __restrict__ C,
                                                    int M, int N, int K) {
    __shared__ unsigned short lds_a[128 * 32];
    __shared__ unsigned short lds_b[128 * 32];
    const int tid  = threadIdx.x;
    const int lane = tid & 63;
    const int wave = tid >> 6;
    const int wrr = wave >> 1, wcc = wave & 1;
    const int l15 = lane & 15, l4 = lane >> 4;
    const int nTilesN = N / 128;
    const long m0 = (long)(blockIdx.x / nTilesN) * 128;
    const long n0 = (long)(blockIdx.x % nTilesN) * 128;
    f32x4 acc[4][4] = {};
    const unsigned short* aSrc = A + (m0 + (tid >> 2)) * (long)K + ((tid & 3) * 8);
    const unsigned short* bSrc = B + (n0 + (tid >> 2)) * (long)K + ((tid & 3) * 8);
    char* aDst = (char*)lds_a + tid * 16;
    char* bDst = (char*)lds_b + tid * 16;
    for (int k0 = 0; k0 < K; k0 += 32) {
#pragma unroll
        for (int i = 0; i < 2; i++) {
            GLL(aSrc + (long)i * 64 * K + k0, aDst + i * 4096);
            GLL(bSrc + (long)i * 64 * K + k0, bDst + i * 4096);
        }
        __syncthreads();
        bf16x8 afr[4], bfr[4];
#pragma unroll
        for (int r = 0; r < 4; r++)
            afr[r] = *(const bf16x8*)&lds_a[(wrr * 64 + r * 16 + l15) * 32 + l4 * 8];
#pragma unroll
        for (int c = 0; c < 4; c++)
            bfr[c] = *(const bf16x8*)&lds_b[(wcc * 64 + c * 16 + l15) * 32 + l4 * 8];
#pragma unroll
        for (int r = 0; r < 4; r++)
#pragma unroll
            for (int c = 0; c < 4; c++)
                acc[r][c] = __builtin_amdgcn_mfma_f32_16x16x32_bf16(afr[r], bfr[c], acc[r][c], 0, 0, 0);
        __syncthreads();
    }
#pragma unroll
    for (int c = 0; c < 4; c++) {
        const long n = n0 + wcc * 64 + c * 16 + l15;
        const float bv = bias[n];
#pragma unroll
        for (int r = 0; r < 4; r++) {
            const long m = m0 + wrr * 64 + r * 16 + l4 * 4;
            float* Cp = C + m * (long)N + n;
#pragma unroll
            for (int j = 0; j < 4; j++)
                Cp[(long)j * N] = acc[r][c][j] + bv;
        }
    }
}

extern "C" void kernel_launch(void* const* d_in, const int* in_sizes, int n_in,
                              void* d_out, int out_size, void* d_ws, size_t ws_size,
                              hipStream_t stream) {
    const float* x    = (const float*)d_in[0];
    const float* w    = (const float*)d_in[1];
    const float* bias = (const float*)d_in[2];
    float* out = (float*)d_out;

    const long Nn = in_sizes[2];             // OUT = 4096
    const long Kk = (long)in_sizes[1] / Nn;  // IN  = 16384
    const long Mm = (long)in_sizes[0] / Kk;  // B*S = 8192

    unsigned short* aB = (unsigned short*)d_ws;
    unsigned short* bB = aB + Mm * Kk;
    cvt_f32_bf16<<<2048, 256, 0, stream>>>(x, aB, Mm * Kk);
    cvt_f32_bf16<<<2048, 256, 0, stream>>>(w, bB, Nn * Kk);

    if ((Mm & 255) == 0 && (Nn & 255) == 0 && (Kk & 127) == 0 && Kk >= 256) {
        const int grid = (int)((Mm >> 8) * (Nn >> 8));
        gemm256_8p<<<grid, 512, 0, stream>>>(aB, bB, bias, out, (int)Mm, (int)Nn, (int)Kk);
    } else {
        const int grid = (int)((Mm / 128) * (Nn / 128));
        gemm_bt_bias<<<grid, 256, 0, stream>>>(aB, bB, bias, out, (int)Mm, (int)Nn, (int)Kk);
    }
}

// Round 8
// 1103.145 us; speedup vs baseline: 4.0127x; 4.0127x over previous
//
#include <hip/hip_runtime.h>
#include <hip/hip_bf16.h>
#include <stdint.h>

typedef float  f32x4  __attribute__((ext_vector_type(4)));
typedef __bf16 bf16x8 __attribute__((ext_vector_type(8)));
typedef unsigned short u16x8 __attribute__((ext_vector_type(8)));

__device__ __forceinline__ unsigned short f2bf_rne(float f) {
    uint32_t x = __float_as_uint(f);
    uint32_t r = x + 0x7FFFu + ((x >> 16) & 1u);
    return (unsigned short)(r >> 16);
}

__global__ __launch_bounds__(256) void cvt_f32_bf16(const float* __restrict__ src,
                                                    unsigned short* __restrict__ dst,
                                                    long n) {
    long i0 = ((long)blockIdx.x * blockDim.x + threadIdx.x) * 8;
    long stride = (long)gridDim.x * blockDim.x * 8;
    for (long j = i0; j + 8 <= n; j += stride) {
        float4 v0 = *(const float4*)(src + j);
        float4 v1 = *(const float4*)(src + j + 4);
        u16x8 o;
        o[0] = f2bf_rne(v0.x); o[1] = f2bf_rne(v0.y);
        o[2] = f2bf_rne(v0.z); o[3] = f2bf_rne(v0.w);
        o[4] = f2bf_rne(v1.x); o[5] = f2bf_rne(v1.y);
        o[6] = f2bf_rne(v1.z); o[7] = f2bf_rne(v1.w);
        *(u16x8*)(dst + j) = o;
    }
}

#define GLL(SRC, DST) __builtin_amdgcn_global_load_lds(                      \
    (const __attribute__((address_space(1))) void*)(SRC),                    \
    (__attribute__((address_space(3))) void*)(DST), 16, 0, 0)
#define BARRIER() asm volatile("s_barrier" ::: "memory")
#define WAITV(N) asm volatile("s_waitcnt vmcnt(" #N ")" ::: "memory")
#define WAITL(N) do { asm volatile("s_waitcnt lgkmcnt(" #N ")" ::: "memory"); \
                      __builtin_amdgcn_sched_barrier(0); } while (0)

// EXACT round-2 body (verified: 112 VGPR, 0 bank conflicts, 1030us best,
// MfmaUtil 49%) with ONE change: two-level XCD super-tile mapping.
// Each XCD's 32 concurrent workgroups form an 8m x 4n super-tile ->
// per-K-step L2 working set 8*64KB + 4*64KB = 768KB (fits 4MiB XCD L2);
// A-panels reused 4x, B-panels 8x within the XCD's L2.
__global__ __launch_bounds__(512, 2) void gemm256_8p(
    const unsigned short* __restrict__ A, const unsigned short* __restrict__ B,
    const float* __restrict__ bias, float* __restrict__ C,
    int M, int N, int K) {
    __shared__ __align__(16) char lds[131072];
    const int tid  = threadIdx.x;
    const int lane = tid & 63;
    const int wave = tid >> 6;
    const int wr  = wave >> 2;   // 0..1
    const int wc  = wave & 3;    // 0..3
    const int l15 = lane & 15;
    const int l4  = lane >> 4;

    // ---- workgroup -> tile mapping (the ONE change vs round 2) ----
    const int nwg = gridDim.x;
    const int Nt  = N >> 8;
    const int Mt  = M >> 8;
    const int bid = blockIdx.x;
    int tm, tn;
    if ((Mt & 7) == 0 && (Nt & 3) == 0 && (nwg & 255) == 0) {
        const int nst = nwg >> 5;        // super-tiles (32 wgs each)
        const int q2  = nst >> 3;        // super-tiles per XCD
        const int xc  = bid & 7;
        const int oo  = bid >> 3;
        const int idx = oo & 31;         // position within super-tile
        const int h   = oo >> 5;         // super-tile index for this XCD
        const int st  = xc * q2 + h;
        const int Mst = Mt >> 3;
        const int stm = st % Mst;
        const int stn = st / Mst;
        tm = stm * 8 + (idx & 7);
        tn = stn * 4 + (idx >> 3);
    } else {
        int qq = nwg >> 3, rr = nwg & 7, xc = bid & 7, oo = bid >> 3;
        int wg = (xc < rr ? xc * (qq + 1) : rr * (qq + 1) + (xc - rr) * qq) + oo;
        tm = wg / Nt; tn = wg % Nt;
    }
    const long m0 = (long)tm << 8;
    const long n0 = (long)tn << 8;

    const int colSw = ((tid & 7) ^ ((tid >> 3) & 7)) << 3;
    const int aRow  = tid >> 3;
    const int bWcLo = tid >> 8;
    const int bR    = (tid >> 3) & 31;
    const long Kl = K;

    auto STAGE_A = [&](int buf, int u, int t) {
        char* dst = lds + (buf << 16) + (u << 14) + tid * 16;
        long col = (long)t * 64 + colSw;
#pragma unroll
        for (int i = 0; i < 2; ++i) {
            const unsigned short* src = A + (m0 + i * 128 + u * 64 + aRow) * Kl + col;
            GLL(src, dst + i * 8192);
        }
    };
    auto STAGE_B = [&](int buf, int u, int t) {
        char* dst = lds + (buf << 16) + 32768 + (u << 14) + tid * 16;
        long col = (long)t * 64 + colSw;
#pragma unroll
        for (int i = 0; i < 2; ++i) {
            const unsigned short* src = B + (n0 + (i * 2 + bWcLo) * 64 + u * 32 + bR) * Kl + col;
            GLL(src, dst + i * 8192);
        }
    };
    auto LDA = [&](int buf, int mh, int m, int kk) -> bf16x8 {
        int off = (((m * 16 + l15) * 64 + kk * 32 + l4 * 8) * 2) ^ ((l15 & 7) << 4);
        return *(const bf16x8*)(lds + (buf << 16) + (mh << 14) + (wr << 13) + off);
    };
    auto LDB = [&](int buf, int nh, int n, int kk) -> bf16x8 {
        int off = (((n * 16 + l15) * 64 + kk * 32 + l4 * 8) * 2) ^ ((l15 & 7) << 4);
        return *(const bf16x8*)(lds + (buf << 16) + 32768 + (nh << 14) + (wc << 12) + off);
    };

    f32x4 acc[8][4] = {};
    bf16x8 af[4][2], bq[2][2];

    const int NT = K >> 6;

    // prologue: tile0 (4 units) -> buf0; vmcnt(4); tile1 minus s3 -> buf1; vmcnt(6)
    STAGE_A(0, 0, 0); STAGE_B(0, 0, 0); STAGE_B(0, 1, 0); STAGE_A(0, 1, 0);
    WAITV(4);
    STAGE_A(1, 0, 1); STAGE_B(1, 1, 1); STAGE_A(1, 1, 1);
    WAITV(6);
    BARRIER();

    for (int t = 0; t < NT; ++t) {
        const int cur = t & 1, nxt = cur ^ 1;
        // ---------- phase 1: quadrant (mh=0, nh=0) ----------
#pragma unroll
        for (int m = 0; m < 4; ++m) { af[m][0] = LDA(cur, 0, m, 0); af[m][1] = LDA(cur, 0, m, 1); }
#pragma unroll
        for (int n = 0; n < 2; ++n) { bq[n][0] = LDB(cur, 0, n, 0); bq[n][1] = LDB(cur, 0, n, 1); }
        if (t + 1 < NT) STAGE_B(nxt, 0, t + 1);   // s3 of tile t+1
        BARRIER(); WAITL(0);
        __builtin_amdgcn_s_setprio(1);
#pragma unroll
        for (int kk = 0; kk < 2; ++kk)
#pragma unroll
            for (int m = 0; m < 4; ++m)
#pragma unroll
                for (int n = 0; n < 2; ++n)
                    acc[m][n] = __builtin_amdgcn_mfma_f32_16x16x32_bf16(af[m][kk], bq[n][kk], acc[m][n], 0, 0, 0);
        __builtin_amdgcn_s_setprio(0);
        BARRIER();
        // ---------- phase 2: quadrant (mh=0, nh=1) ----------
#pragma unroll
        for (int n = 0; n < 2; ++n) { bq[n][0] = LDB(cur, 1, n, 0); bq[n][1] = LDB(cur, 1, n, 1); }
        if (t + 2 < NT) STAGE_A(cur, 0, t + 2);   // s1 of tile t+2
        BARRIER(); WAITL(0);
        __builtin_amdgcn_s_setprio(1);
#pragma unroll
        for (int kk = 0; kk < 2; ++kk)
#pragma unroll
            for (int m = 0; m < 4; ++m)
#pragma unroll
                for (int n = 0; n < 2; ++n)
                    acc[m][2 + n] = __builtin_amdgcn_mfma_f32_16x16x32_bf16(af[m][kk], bq[n][kk], acc[m][2 + n], 0, 0, 0);
        __builtin_amdgcn_s_setprio(0);
        BARRIER();
        // ---------- phase 3: quadrant (mh=1, nh=1) ----------
#pragma unroll
        for (int m = 0; m < 4; ++m) { af[m][0] = LDA(cur, 1, m, 0); af[m][1] = LDA(cur, 1, m, 1); }
        if (t + 2 < NT) STAGE_B(cur, 1, t + 2);   // s4 of tile t+2
        BARRIER(); WAITL(0);
        __builtin_amdgcn_s_setprio(1);
#pragma unroll
        for (int kk = 0; kk < 2; ++kk)
#pragma unroll
            for (int m = 0; m < 4; ++m)
#pragma unroll
                for (int n = 0; n < 2; ++n)
                    acc[4 + m][2 + n] = __builtin_amdgcn_mfma_f32_16x16x32_bf16(af[m][kk], bq[n][kk], acc[4 + m][2 + n], 0, 0, 0);
        __builtin_amdgcn_s_setprio(0);
        BARRIER();
        // ---------- phase 4: quadrant (mh=1, nh=0) ----------
#pragma unroll
        for (int n = 0; n < 2; ++n) { bq[n][0] = LDB(cur, 0, n, 0); bq[n][1] = LDB(cur, 0, n, 1); }
        if (t + 2 < NT) STAGE_A(cur, 1, t + 2);   // s2 of tile t+2
        if (t == NT - 2) { WAITV(0); }
        else             { WAITV(6); }
        BARRIER(); WAITL(0);
        __builtin_amdgcn_s_setprio(1);
#pragma unroll
        for (int kk = 0; kk < 2; ++kk)
#pragma unroll
            for (int m = 0; m < 4; ++m)
#pragma unroll
                for (int n = 0; n < 2; ++n)
                    acc[4 + m][n] = __builtin_amdgcn_mfma_f32_16x16x32_bf16(af[m][kk], bq[n][kk], acc[4 + m][n], 0, 0, 0);
        __builtin_amdgcn_s_setprio(0);
        BARRIER();
    }

    // epilogue: D mapping col = l15, row = l4*4 + j within each 16x16 fragment
#pragma unroll
    for (int nf = 0; nf < 4; ++nf) {
        const long col = n0 + wc * 64 + nf * 16 + l15;
        const float bv = bias[col];
#pragma unroll
        for (int mf = 0; mf < 8; ++mf) {
            float* Cp = C + (m0 + wr * 128 + mf * 16 + l4 * 4) * (long)N + col;
#pragma unroll
            for (int j = 0; j < 4; ++j)
                Cp[(long)j * N] = acc[mf][nf][j] + bv;
        }
    }
}

// fallback: m97-structure 128x128 (verified round 1)
__global__ __launch_bounds__(256) void gemm_bt_bias(const unsigned short* __restrict__ A,
                                                    const unsigned short* __restrict__ B,
                                                    const float* __restrict__ bias,
                                                    float* __restrict__ C,
                                                    int M, int N, int K) {
    __shared__ unsigned short lds_a[128 * 32];
    __shared__ unsigned short lds_b[128 * 32];
    const int tid  = threadIdx.x;
    const int lane = tid & 63;
    const int wave = tid >> 6;
    const int wrr = wave >> 1, wcc = wave & 1;
    const int l15 = lane & 15, l4 = lane >> 4;
    const int nTilesN = N / 128;
    const long m0 = (long)(blockIdx.x / nTilesN) * 128;
    const long n0 = (long)(blockIdx.x % nTilesN) * 128;
    f32x4 acc[4][4] = {};
    const unsigned short* aSrc = A + (m0 + (tid >> 2)) * (long)K + ((tid & 3) * 8);
    const unsigned short* bSrc = B + (n0 + (tid >> 2)) * (long)K + ((tid & 3) * 8);
    char* aDst = (char*)lds_a + tid * 16;
    char* bDst = (char*)lds_b + tid * 16;
    for (int k0 = 0; k0 < K; k0 += 32) {
#pragma unroll
        for (int i = 0; i < 2; i++) {
            GLL(aSrc + (long)i * 64 * K + k0, aDst + i * 4096);
            GLL(bSrc + (long)i * 64 * K + k0, bDst + i * 4096);
        }
        __syncthreads();
        bf16x8 afr[4], bfr[4];
#pragma unroll
        for (int r = 0; r < 4; r++)
            afr[r] = *(const bf16x8*)&lds_a[(wrr * 64 + r * 16 + l15) * 32 + l4 * 8];
#pragma unroll
        for (int c = 0; c < 4; c++)
            bfr[c] = *(const bf16x8*)&lds_b[(wcc * 64 + c * 16 + l15) * 32 + l4 * 8];
#pragma unroll
        for (int r = 0; r < 4; r++)
#pragma unroll
            for (int c = 0; c < 4; c++)
                acc[r][c] = __builtin_amdgcn_mfma_f32_16x16x32_bf16(afr[r], bfr[c], acc[r][c], 0, 0, 0);
        __syncthreads();
    }
#pragma unroll
    for (int c = 0; c < 4; c++) {
        const long n = n0 + wcc * 64 + c * 16 + l15;
        const float bv = bias[n];
#pragma unroll
        for (int r = 0; r < 4; r++) {
            const long m = m0 + wrr * 64 + r * 16 + l4 * 4;
            float* Cp = C + m * (long)N + n;
#pragma unroll
            for (int j = 0; j < 4; j++)
                Cp[(long)j * N] = acc[r][c][j] + bv;
        }
    }
}

extern "C" void kernel_launch(void* const* d_in, const int* in_sizes, int n_in,
                              void* d_out, int out_size, void* d_ws, size_t ws_size,
                              hipStream_t stream) {
    const float* x    = (const float*)d_in[0];
    const float* w    = (const float*)d_in[1];
    const float* bias = (const float*)d_in[2];
    float* out = (float*)d_out;

    const long Nn = in_sizes[2];             // OUT = 4096
    const long Kk = (long)in_sizes[1] / Nn;  // IN  = 16384
    const long Mm = (long)in_sizes[0] / Kk;  // B*S = 8192

    unsigned short* aB = (unsigned short*)d_ws;
    unsigned short* bB = aB + Mm * Kk;
    cvt_f32_bf16<<<2048, 256, 0, stream>>>(x, aB, Mm * Kk);
    cvt_f32_bf16<<<2048, 256, 0, stream>>>(w, bB, Nn * Kk);

    if ((Mm & 255) == 0 && (Nn & 255) == 0 && (Kk & 127) == 0 && Kk >= 256) {
        const int grid = (int)((Mm >> 8) * (Nn >> 8));
        gemm256_8p<<<grid, 512, 0, stream>>>(aB, bB, bias, out, (int)Mm, (int)Nn, (int)Kk);
    } else {
        const int grid = (int)((Mm / 128) * (Nn / 128));
        gemm_bt_bias<<<grid, 256, 0, stream>>>(aB, bB, bias, out, (int)Mm, (int)Nn, (int)Kk);
    }
}